// Round 19
// baseline (106.325 us; speedup 1.0000x reference)
//
#include <hip/hip_runtime.h>
#include <hip/hip_bf16.h>

#define D 64
#define NODES_PER_BIN 256
#define BIN_SHIFT 8
#define CAP 5120          // padded per-bin capacity (mean 4096, sd ~64 -> +16 sigma)
#define TILE 2048
#define EPT 8             // TILE / 256
#define WSTR 72           // padded LDS stride for transposed W (bank-spread)

typedef short bf16x8 __attribute__((ext_vector_type(8)));
typedef float f32x4 __attribute__((ext_vector_type(4)));
typedef unsigned short u16x8 __attribute__((ext_vector_type(8)));

// bf16 helpers (finite data only)
__device__ __forceinline__ float bf2f(unsigned short u) {
    union { unsigned int i; float f; } c; c.i = (unsigned int)u << 16; return c.f;
}
__device__ __forceinline__ unsigned short f2bf(float f) {
    union { float f; unsigned int i; } c; c.f = f;
    unsigned int x = c.i;
    return (unsigned short)((x + 0x7fffu + ((x >> 16) & 1u)) >> 16);  // RNE
}

// tiny zero kernel (1 block, ~2 us)
__global__ void k_zero_i(int* __restrict__ p, int n) {
    int i = threadIdx.x;
    if (i < n) p[i] = 0;
}

// ---- passA v2: direct-write multisplit into PADDED bin segments --------
// packed word: src | dstLocal<<17   (requires N <= 2^17)
__global__ __launch_bounds__(256) void k_passA(const int* __restrict__ src,
                                               const int* __restrict__ dst,
                                               int* __restrict__ cursor,      // [NBINS], zeroed
                                               int* __restrict__ binned,      // [NBINS*CAP]
                                               int E, int NBINS) {
    __shared__ int hist[512];
    __shared__ int reservedBase[512];
    int tid = threadIdx.x;
    long long t0 = (long long)blockIdx.x * TILE;
    int cnt_tile = (int)((E - t0 < TILE) ? (E - t0) : TILE);

    for (int i = tid; i < 512; i += 256) hist[i] = 0;
    __syncthreads();

    int val[EPT]; int bn[EPT]; int rk[EPT];
#pragma unroll
    for (int k = 0; k < EPT; ++k) {
        int i = k * 256 + tid;
        if (i < cnt_tile) {
            int e = (int)t0 + i;
            int s = src[e], d = dst[e];
            bn[k] = d >> BIN_SHIFT;
            val[k] = s | ((d & (NODES_PER_BIN - 1)) << 17);
            rk[k] = atomicAdd(&hist[bn[k]], 1);   // rank within block
        } else { bn[k] = -1; val[k] = 0; rk[k] = 0; }
    }
    __syncthreads();
    for (int i = tid; i < NBINS; i += 256)
        reservedBase[i] = (hist[i] > 0) ? atomicAdd(&cursor[i], hist[i]) : 0;
    __syncthreads();
#pragma unroll
    for (int k = 0; k < EPT; ++k)
        if (bn[k] >= 0)
            binned[bn[k] * CAP + reservedBase[bn[k]] + rk[k]] = val[k];
}

// ---- passB: per-bin LDS counting sort -> sorted_src (padded), row_ptr,
//      counts, dinv. row_ptr = b*CAP + local offset. ----
__global__ __launch_bounds__(256) void k_passB(const int* __restrict__ binned,
                                               const int* __restrict__ binCount,  // = cursor after passA
                                               int* __restrict__ sorted_src,      // [NBINS*CAP]
                                               int* __restrict__ row_ptr,
                                               int* __restrict__ counts,
                                               float* __restrict__ dinv, int N) {
    __shared__ int eLDS[CAP];
    __shared__ int srt[CAP];
    __shared__ int cnt[NODES_PER_BIN];
    __shared__ int nodeOff[NODES_PER_BIN];
    __shared__ int sA[NODES_PER_BIN], sB[NODES_PER_BIN];
    int tid = threadIdx.x;
    int b = blockIdx.x;
    int lo = b << BIN_SHIFT;
    int nNodes = N - lo; if (nNodes > NODES_PER_BIN) nNodes = NODES_PER_BIN;
    int base = b * CAP;
    int size = binCount[b]; if (size > CAP) size = CAP;

    for (int i = tid; i < size; i += 256) eLDS[i] = binned[base + i];
    cnt[tid] = 0;
    __syncthreads();
    for (int i = tid; i < size; i += 256) atomicAdd(&cnt[eLDS[i] >> 17], 1);
    __syncthreads();
    sA[tid] = cnt[tid];
    __syncthreads();
    int *a = sA, *bb = sB;
    for (int dd = 1; dd < 256; dd <<= 1) {
        bb[tid] = a[tid] + (tid >= dd ? a[tid - dd] : 0);
        __syncthreads();
        int* t = a; a = bb; bb = t;
    }
    nodeOff[tid] = (tid > 0) ? a[tid - 1] : 0;
    __syncthreads();
    if (tid < nNodes) {
        int c = cnt[tid];
        row_ptr[lo + tid] = base + nodeOff[tid];
        counts[lo + tid] = c;
        dinv[lo + tid] = rsqrtf(1.0f + (float)c);
    }
    __syncthreads();
    cnt[tid] = 0;
    __syncthreads();
    for (int i = tid; i < size; i += 256) {
        int v = eLDS[i];
        int dl = v >> 17;
        int r = atomicAdd(&cnt[dl], 1);
        srt[nodeOff[dl] + r] = v & 0x1FFFF;
    }
    __syncthreads();
    for (int i = tid; i < size; i += 256) sorted_src[base + i] = srt[i];
}

// ---------------- g = bf16((x @ W) * dinv[row]) via MFMA, persistent ----
__global__ __launch_bounds__(256) void k_gemm_v4(const float* __restrict__ x,
                                                 const float* __restrict__ W,
                                                 const float* __restrict__ dinv,
                                                 unsigned short* __restrict__ g, int N) {
    __shared__ unsigned short WtHi[D * WSTR];  // 9 KB
    __shared__ unsigned short WtLo[D * WSTR];  // 9 KB
    int tid = threadIdx.x;
    for (int idx = tid; idx < D * D; idx += 256) {
        int k = idx >> 6, j = idx & 63;
        float w = W[idx];                    // W[k][j]
        unsigned short hi = f2bf(w);
        WtHi[j * WSTR + k] = hi;
        WtLo[j * WSTR + k] = f2bf(w - bf2f(hi));
    }
    __syncthreads();

    int lane = tid & 63;
    int wid  = tid >> 6;
    int lcol = lane & 15;
    int lkg  = lane >> 4;

    bf16x8 Bhi[2][4], Blo[2][4];
#pragma unroll
    for (int s = 0; s < 2; ++s)
#pragma unroll
        for (int n = 0; n < 4; ++n) {
            int j = n * 16 + lcol;
            int k = s * 32 + lkg * 8;
            Bhi[s][n] = *(const bf16x8*)&WtHi[j * WSTR + k];
            Blo[s][n] = *(const bf16x8*)&WtLo[j * WSTR + k];
        }

    const int nTiles = (N + 15) >> 4;
    const int stride = gridDim.x * 4;
    for (int t = blockIdx.x * 4 + wid; t < nTiles; t += stride) {
        int r0 = t * 16;
        int arow = r0 + lcol;
        bool rok = (arow < N);
        bf16x8 Ahi[2], Alo[2];
#pragma unroll
        for (int s = 0; s < 2; ++s) {
            float4 v0{0.f,0.f,0.f,0.f}, v1{0.f,0.f,0.f,0.f};
            if (rok) {
                const float4* p = (const float4*)&x[(size_t)arow * D + s * 32 + lkg * 8];
                v0 = p[0]; v1 = p[1];
            }
            float xv[8] = {v0.x, v0.y, v0.z, v0.w, v1.x, v1.y, v1.z, v1.w};
#pragma unroll
            for (int e = 0; e < 8; ++e) {
                unsigned short hi = f2bf(xv[e]);
                Ahi[s][e] = (short)hi;
                Alo[s][e] = (short)f2bf(xv[e] - bf2f(hi));
            }
        }

        f32x4 acc[4];
#pragma unroll
        for (int n = 0; n < 4; ++n) {
            f32x4 c = {0.f, 0.f, 0.f, 0.f};
            c = __builtin_amdgcn_mfma_f32_16x16x32_bf16(Ahi[0], Bhi[0][n], c, 0, 0, 0);
            c = __builtin_amdgcn_mfma_f32_16x16x32_bf16(Ahi[1], Bhi[1][n], c, 0, 0, 0);
            c = __builtin_amdgcn_mfma_f32_16x16x32_bf16(Alo[0], Bhi[0][n], c, 0, 0, 0);
            c = __builtin_amdgcn_mfma_f32_16x16x32_bf16(Alo[1], Bhi[1][n], c, 0, 0, 0);
            c = __builtin_amdgcn_mfma_f32_16x16x32_bf16(Ahi[0], Blo[0][n], c, 0, 0, 0);
            c = __builtin_amdgcn_mfma_f32_16x16x32_bf16(Ahi[1], Blo[1][n], c, 0, 0, 0);
            acc[n] = c;
        }

#pragma unroll
        for (int i = 0; i < 4; ++i) {
            int orow = r0 + lkg * 4 + i;
            if (orow < N) {
                float dv = dinv[orow];
#pragma unroll
                for (int n = 0; n < 4; ++n)
                    g[(size_t)orow * D + n * 16 + lcol] = f2bf(acc[n][i] * dv);
            }
        }
    }
}

// ---------------- aggregate v8: 2 waves per node (fix grid-limited occ) --
// Wave w of a 256-thr block: node n = blockIdx*2 + (w>>1), half h = w&1.
// Half h processes edge-groups jg % 2 == h (8 edges/group via ushort8
// eighth-wave gather). Partials combine through LDS; half-0 writes out.
__global__ __launch_bounds__(256) void k_aggregate8(const int* __restrict__ row_ptr,
                                                    const int* __restrict__ counts,
                                                    const int* __restrict__ sorted_src,
                                                    const u16x8* __restrict__ g8,
                                                    const float* __restrict__ dinv,
                                                    const float* __restrict__ b,
                                                    float* __restrict__ out, int N) {
    __shared__ float part[4][8][8];   // [wave][p8][feat]
    int tid = threadIdx.x;
    int w = tid >> 6;
    int lane = tid & 63;
    int n = blockIdx.x * 2 + (w >> 1);
    int h = w & 1;
    int q8 = lane >> 3;
    int p8 = lane & 7;
    bool nok = (n < N);
    int start = 0, cnt = 0;
    if (nok) { start = row_ptr[n]; cnt = counts[n]; }
    const int* sp = sorted_src + start;
    int safe = nok ? n : 0;

    float a0 = 0.f, a1 = 0.f, a2 = 0.f, a3 = 0.f;
    float a4 = 0.f, a5 = 0.f, a6 = 0.f, a7 = 0.f;
    if (nok && h == 0 && q8 == 0) {   // self-loop term once
        u16x8 v = g8[(size_t)n * 8 + p8];
        a0 = bf2f(v[0]); a1 = bf2f(v[1]); a2 = bf2f(v[2]); a3 = bf2f(v[3]);
        a4 = bf2f(v[4]); a5 = bf2f(v[5]); a6 = bf2f(v[6]); a7 = bf2f(v[7]);
    }

#define LIDX8(jg, I, M)                                        \
    {                                                          \
        int e_ = (jg) * 8 + q8;                                \
        bool ok_ = (e_ < cnt);                                 \
        I = ok_ ? sp[e_] : safe;                               \
        M = ok_ ? 1.f : 0.f;                                   \
    }
#define CONS8(V, M)                                            \
    {                                                          \
        a0 = fmaf(M, bf2f(V[0]), a0);                          \
        a1 = fmaf(M, bf2f(V[1]), a1);                          \
        a2 = fmaf(M, bf2f(V[2]), a2);                          \
        a3 = fmaf(M, bf2f(V[3]), a3);                          \
        a4 = fmaf(M, bf2f(V[4]), a4);                          \
        a5 = fmaf(M, bf2f(V[5]), a5);                          \
        a6 = fmaf(M, bf2f(V[6]), a6);                          \
        a7 = fmaf(M, bf2f(V[7]), a7);                          \
    }

    // flat-issue groups h and h+2 (combined halves cover 32 edges)
    int i0, i1; float m0, m1;
    LIDX8(h, i0, m0); LIDX8(h + 2, i1, m1);
    u16x8 u0 = g8[(size_t)i0 * 8 + p8];
    u16x8 u1 = g8[(size_t)i1 * 8 + p8];
    CONS8(u0, m0); CONS8(u1, m1);

    int ng = (cnt + 7) >> 3;
    for (int jg = 4 + h; jg < ng; jg += 2) {   // rare: cnt > 32
        int I; float M;
        LIDX8(jg, I, M);
        u16x8 U = g8[(size_t)I * 8 + p8];
        CONS8(U, M);
    }
#undef LIDX8
#undef CONS8

    // fold the 8 edge-slots (q8) down to q8==0
#define FOLD(A) A += __shfl_xor(A, 8, 64); A += __shfl_xor(A, 16, 64); A += __shfl_xor(A, 32, 64);
    FOLD(a0) FOLD(a1) FOLD(a2) FOLD(a3) FOLD(a4) FOLD(a5) FOLD(a6) FOLD(a7)
#undef FOLD

    if (q8 == 0) {
        part[w][p8][0] = a0; part[w][p8][1] = a1; part[w][p8][2] = a2; part[w][p8][3] = a3;
        part[w][p8][4] = a4; part[w][p8][5] = a5; part[w][p8][6] = a6; part[w][p8][7] = a7;
    }
    __syncthreads();
    if (nok && h == 0 && q8 == 0) {   // combine partner half, epilogue
        a0 += part[w + 1][p8][0]; a1 += part[w + 1][p8][1];
        a2 += part[w + 1][p8][2]; a3 += part[w + 1][p8][3];
        a4 += part[w + 1][p8][4]; a5 += part[w + 1][p8][5];
        a6 += part[w + 1][p8][6]; a7 += part[w + 1][p8][7];
        float dv = dinv[n];
        const float4* b4 = (const float4*)b;
        float4 bl = b4[p8 * 2 + 0];
        float4 bh = b4[p8 * 2 + 1];
        float4 r0, r1;
        r0.x = fmaxf(fmaf(a0, dv, bl.x), 0.f);
        r0.y = fmaxf(fmaf(a1, dv, bl.y), 0.f);
        r0.z = fmaxf(fmaf(a2, dv, bl.z), 0.f);
        r0.w = fmaxf(fmaf(a3, dv, bl.w), 0.f);
        r1.x = fmaxf(fmaf(a4, dv, bh.x), 0.f);
        r1.y = fmaxf(fmaf(a5, dv, bh.y), 0.f);
        r1.z = fmaxf(fmaf(a6, dv, bh.z), 0.f);
        r1.w = fmaxf(fmaf(a7, dv, bh.w), 0.f);
        float4* o4 = (float4*)out;
        o4[(size_t)n * 16 + p8 * 2 + 0] = r0;
        o4[(size_t)n * 16 + p8 * 2 + 1] = r1;
    }
}

// ---------------- tier-3 (atomic fallback) ----------------

__global__ void k_deg_init(float* __restrict__ deg, int N) {
    int i = blockIdx.x * blockDim.x + threadIdx.x;
    if (i < N) deg[i] = 1.0f;
}
__global__ void k_deg_count(const int* __restrict__ dst, float* __restrict__ deg, int E) {
    int i = blockIdx.x * blockDim.x + threadIdx.x;
    if (i < E) atomicAdd(&deg[dst[i]], 1.0f);
}
__global__ void k_dinv_f(float* __restrict__ deg, int N) {
    int i = blockIdx.x * blockDim.x + threadIdx.x;
    if (i < N) deg[i] = rsqrtf(deg[i]);
}
__global__ __launch_bounds__(256) void k_gemm_fb(const float* __restrict__ x, const float* __restrict__ W,
                                                 const float* __restrict__ dinv, float* __restrict__ g,
                                                 float* __restrict__ acc, int N) {
    __shared__ float Ws[D * D];
    __shared__ float xs[4][D];
    int tid = threadIdx.x;
    for (int t = tid; t < D * D; t += 256) Ws[t] = W[t];
    int rg = tid >> 6, j = tid & 63;
    int r = blockIdx.x * 4 + rg;
    if (r < N) xs[rg][j] = x[r * D + j];
    __syncthreads();
    if (r < N) {
        float s = 0.f;
#pragma unroll
        for (int k = 0; k < D; ++k) s = fmaf(xs[rg][k], Ws[k * D + j], s);
        s *= dinv[r];
        g[r * D + j] = s;
        acc[r * D + j] = s;
    }
}
__global__ __launch_bounds__(256) void k_scatter_fb(const int* __restrict__ src, const int* __restrict__ dst,
                                                    const float* __restrict__ g, float* __restrict__ acc, int E) {
    long long idx = (long long)blockIdx.x * blockDim.x + threadIdx.x;
    int e = (int)(idx >> 6), j = (int)(idx & 63);
    if (e < E) atomicAdd(&acc[dst[e] * D + j], g[src[e] * D + j]);
}
__global__ void k_final_fb(float* __restrict__ out, const float* __restrict__ dinv,
                           const float* __restrict__ b, int N) {
    int idx = blockIdx.x * blockDim.x + threadIdx.x;
    if (idx < N * D) {
        int r = idx >> 6, j = idx & 63;
        float v = out[idx] * dinv[r] + b[j];
        out[idx] = v > 0.f ? v : 0.f;
    }
}

// ---------------- launch ----------------

extern "C" void kernel_launch(void* const* d_in, const int* in_sizes, int n_in,
                              void* d_out, int out_size, void* d_ws, size_t ws_size,
                              hipStream_t stream) {
    const float* x  = (const float*)d_in[0];
    const int*   ei = (const int*)d_in[1];
    const float* W  = (const float*)d_in[2];
    const float* b  = (const float*)d_in[3];
    float* out = (float*)d_out;

    const int N = in_sizes[0] / D;   // 80000
    const int E = in_sizes[1] / 2;   // 1280000
    const int* src = ei;
    const int* dst = ei + E;
    const int NBINS = (N + NODES_PER_BIN - 1) >> BIN_SHIFT;

    size_t off = 0;
    auto take = [&](size_t bytes) { size_t p = off; off = (off + bytes + 255) & ~(size_t)255; return p; };
    char* base = (char*)d_ws;
    size_t o_counts  = take((size_t)N * 4);
    size_t o_dinv    = take((size_t)N * 4);
    size_t o_rowptr  = take((size_t)N * 4);
    size_t o_cursor  = take(512 * 4);
    size_t o_sorted  = take((size_t)NBINS * CAP * 4);   // padded
    size_t o_binned  = take((size_t)NBINS * CAP * 4);   // padded
    size_t o_g       = take((size_t)N * D * 2);         // bf16 g
    size_t req1 = off;

    bool tier1_ok = (ws_size >= req1) && (N <= (1 << 17)) && (NBINS <= 512);

    if (tier1_ok) {
        int* counts     = (int*)(base + o_counts);
        float* dinv     = (float*)(base + o_dinv);
        int* row_ptr    = (int*)(base + o_rowptr);
        int* cursor     = (int*)(base + o_cursor);
        int* sorted_src = (int*)(base + o_sorted);
        int* binned     = (int*)(base + o_binned);
        unsigned short* g = (unsigned short*)(base + o_g);

        k_zero_i<<<1, 512, 0, stream>>>(cursor, NBINS);
        k_passA<<<(E + TILE - 1) / TILE, 256, 0, stream>>>(src, dst, cursor, binned, E, NBINS);
        k_passB<<<NBINS, 256, 0, stream>>>(binned, cursor, sorted_src, row_ptr, counts, dinv, N);
        k_gemm_v4<<<625, 256, 0, stream>>>(x, W, dinv, g, N);
        k_aggregate8<<<(N + 1) / 2, 256, 0, stream>>>(row_ptr, counts, sorted_src,
                                                      (const u16x8*)g, dinv, b, out, N);
        return;
    }

    // tier 3: atomic fallback (fp32 end-to-end, ~21 MB ws)
    {
        float* deg = (float*)d_ws;
        float* g   = (float*)((char*)d_ws + (size_t)N * sizeof(float));
        k_deg_init<<<(N + 255) / 256, 256, 0, stream>>>(deg, N);
        k_deg_count<<<(E + 255) / 256, 256, 0, stream>>>(dst, deg, E);
        k_dinv_f<<<(N + 255) / 256, 256, 0, stream>>>(deg, N);
        k_gemm_fb<<<(N + 3) / 4, 256, 0, stream>>>(x, W, deg, g, out, N);
        long long total = (long long)E * D;
        k_scatter_fb<<<(int)((total + 255) / 256), 256, 0, stream>>>(src, dst, g, out, E);
        k_final_fb<<<(N * D + 255) / 256, 256, 0, stream>>>(out, deg, b, N);
    }
}

// Round 20
// 85.289 us; speedup vs baseline: 1.2467x; 1.2467x over previous
//
#include <hip/hip_runtime.h>
#include <hip/hip_bf16.h>

#define D 64
#define NODES_PER_BIN 256
#define BIN_SHIFT 8
#define CAP 5120          // padded per-bin capacity (mean 4096, sd ~64 -> +16 sigma)
#define TILE 2048
#define EPT 8             // TILE / 256
#define WSTR 72           // padded LDS stride for transposed W (bank-spread)

typedef short bf16x8 __attribute__((ext_vector_type(8)));
typedef float f32x4 __attribute__((ext_vector_type(4)));
typedef unsigned short u16x8 __attribute__((ext_vector_type(8)));

// bf16 helpers (finite data only)
__device__ __forceinline__ float bf2f(unsigned short u) {
    union { unsigned int i; float f; } c; c.i = (unsigned int)u << 16; return c.f;
}
__device__ __forceinline__ unsigned short f2bf(float f) {
    union { float f; unsigned int i; } c; c.f = f;
    unsigned int x = c.i;
    return (unsigned short)((x + 0x7fffu + ((x >> 16) & 1u)) >> 16);  // RNE
}

// tiny zero kernel (1 block, ~2 us)
__global__ void k_zero_i(int* __restrict__ p, int n) {
    int i = threadIdx.x;
    if (i < n) p[i] = 0;
}

// ---- passA v2: direct-write multisplit into PADDED bin segments --------
// packed word: src | dstLocal<<17   (requires N <= 2^17)
__global__ __launch_bounds__(256) void k_passA(const int* __restrict__ src,
                                               const int* __restrict__ dst,
                                               int* __restrict__ cursor,      // [NBINS], zeroed
                                               int* __restrict__ binned,      // [NBINS*CAP]
                                               int E, int NBINS) {
    __shared__ int hist[512];
    __shared__ int reservedBase[512];
    int tid = threadIdx.x;
    long long t0 = (long long)blockIdx.x * TILE;
    int cnt_tile = (int)((E - t0 < TILE) ? (E - t0) : TILE);

    for (int i = tid; i < 512; i += 256) hist[i] = 0;
    __syncthreads();

    int val[EPT]; int bn[EPT]; int rk[EPT];
#pragma unroll
    for (int k = 0; k < EPT; ++k) {
        int i = k * 256 + tid;
        if (i < cnt_tile) {
            int e = (int)t0 + i;
            int s = src[e], d = dst[e];
            bn[k] = d >> BIN_SHIFT;
            val[k] = s | ((d & (NODES_PER_BIN - 1)) << 17);
            rk[k] = atomicAdd(&hist[bn[k]], 1);   // rank within block
        } else { bn[k] = -1; val[k] = 0; rk[k] = 0; }
    }
    __syncthreads();
    for (int i = tid; i < NBINS; i += 256)
        reservedBase[i] = (hist[i] > 0) ? atomicAdd(&cursor[i], hist[i]) : 0;
    __syncthreads();
#pragma unroll
    for (int k = 0; k < EPT; ++k)
        if (bn[k] >= 0)
            binned[bn[k] * CAP + reservedBase[bn[k]] + rk[k]] = val[k];
}

// ---- passB: per-bin LDS counting sort -> sorted_src (padded), row_ptr,
//      counts, dinv. row_ptr = b*CAP + local offset. ----
__global__ __launch_bounds__(256) void k_passB(const int* __restrict__ binned,
                                               const int* __restrict__ binCount,  // = cursor after passA
                                               int* __restrict__ sorted_src,      // [NBINS*CAP]
                                               int* __restrict__ row_ptr,
                                               int* __restrict__ counts,
                                               float* __restrict__ dinv, int N) {
    __shared__ int eLDS[CAP];
    __shared__ int srt[CAP];
    __shared__ int cnt[NODES_PER_BIN];
    __shared__ int nodeOff[NODES_PER_BIN];
    __shared__ int sA[NODES_PER_BIN], sB[NODES_PER_BIN];
    int tid = threadIdx.x;
    int b = blockIdx.x;
    int lo = b << BIN_SHIFT;
    int nNodes = N - lo; if (nNodes > NODES_PER_BIN) nNodes = NODES_PER_BIN;
    int base = b * CAP;
    int size = binCount[b]; if (size > CAP) size = CAP;

    for (int i = tid; i < size; i += 256) eLDS[i] = binned[base + i];
    cnt[tid] = 0;
    __syncthreads();
    for (int i = tid; i < size; i += 256) atomicAdd(&cnt[eLDS[i] >> 17], 1);
    __syncthreads();
    sA[tid] = cnt[tid];
    __syncthreads();
    int *a = sA, *bb = sB;
    for (int dd = 1; dd < 256; dd <<= 1) {
        bb[tid] = a[tid] + (tid >= dd ? a[tid - dd] : 0);
        __syncthreads();
        int* t = a; a = bb; bb = t;
    }
    nodeOff[tid] = (tid > 0) ? a[tid - 1] : 0;
    __syncthreads();
    if (tid < nNodes) {
        int c = cnt[tid];
        row_ptr[lo + tid] = base + nodeOff[tid];
        counts[lo + tid] = c;
        dinv[lo + tid] = rsqrtf(1.0f + (float)c);
    }
    __syncthreads();
    cnt[tid] = 0;
    __syncthreads();
    for (int i = tid; i < size; i += 256) {
        int v = eLDS[i];
        int dl = v >> 17;
        int r = atomicAdd(&cnt[dl], 1);
        srt[nodeOff[dl] + r] = v & 0x1FFFF;
    }
    __syncthreads();
    for (int i = tid; i < size; i += 256) sorted_src[base + i] = srt[i];
}

// ---------------- g = bf16((x @ W) * dinv[row]) via MFMA, persistent ----
__global__ __launch_bounds__(256) void k_gemm_v4(const float* __restrict__ x,
                                                 const float* __restrict__ W,
                                                 const float* __restrict__ dinv,
                                                 unsigned short* __restrict__ g, int N) {
    __shared__ unsigned short WtHi[D * WSTR];  // 9 KB
    __shared__ unsigned short WtLo[D * WSTR];  // 9 KB
    int tid = threadIdx.x;
    for (int idx = tid; idx < D * D; idx += 256) {
        int k = idx >> 6, j = idx & 63;
        float w = W[idx];                    // W[k][j]
        unsigned short hi = f2bf(w);
        WtHi[j * WSTR + k] = hi;
        WtLo[j * WSTR + k] = f2bf(w - bf2f(hi));
    }
    __syncthreads();

    int lane = tid & 63;
    int wid  = tid >> 6;
    int lcol = lane & 15;
    int lkg  = lane >> 4;

    bf16x8 Bhi[2][4], Blo[2][4];
#pragma unroll
    for (int s = 0; s < 2; ++s)
#pragma unroll
        for (int n = 0; n < 4; ++n) {
            int j = n * 16 + lcol;
            int k = s * 32 + lkg * 8;
            Bhi[s][n] = *(const bf16x8*)&WtHi[j * WSTR + k];
            Blo[s][n] = *(const bf16x8*)&WtLo[j * WSTR + k];
        }

    const int nTiles = (N + 15) >> 4;
    const int stride = gridDim.x * 4;
    for (int t = blockIdx.x * 4 + wid; t < nTiles; t += stride) {
        int r0 = t * 16;
        int arow = r0 + lcol;
        bool rok = (arow < N);
        bf16x8 Ahi[2], Alo[2];
#pragma unroll
        for (int s = 0; s < 2; ++s) {
            float4 v0{0.f,0.f,0.f,0.f}, v1{0.f,0.f,0.f,0.f};
            if (rok) {
                const float4* p = (const float4*)&x[(size_t)arow * D + s * 32 + lkg * 8];
                v0 = p[0]; v1 = p[1];
            }
            float xv[8] = {v0.x, v0.y, v0.z, v0.w, v1.x, v1.y, v1.z, v1.w};
#pragma unroll
            for (int e = 0; e < 8; ++e) {
                unsigned short hi = f2bf(xv[e]);
                Ahi[s][e] = (short)hi;
                Alo[s][e] = (short)f2bf(xv[e] - bf2f(hi));
            }
        }

        f32x4 acc[4];
#pragma unroll
        for (int n = 0; n < 4; ++n) {
            f32x4 c = {0.f, 0.f, 0.f, 0.f};
            c = __builtin_amdgcn_mfma_f32_16x16x32_bf16(Ahi[0], Bhi[0][n], c, 0, 0, 0);
            c = __builtin_amdgcn_mfma_f32_16x16x32_bf16(Ahi[1], Bhi[1][n], c, 0, 0, 0);
            c = __builtin_amdgcn_mfma_f32_16x16x32_bf16(Alo[0], Bhi[0][n], c, 0, 0, 0);
            c = __builtin_amdgcn_mfma_f32_16x16x32_bf16(Alo[1], Bhi[1][n], c, 0, 0, 0);
            c = __builtin_amdgcn_mfma_f32_16x16x32_bf16(Ahi[0], Blo[0][n], c, 0, 0, 0);
            c = __builtin_amdgcn_mfma_f32_16x16x32_bf16(Ahi[1], Blo[1][n], c, 0, 0, 0);
            acc[n] = c;
        }

#pragma unroll
        for (int i = 0; i < 4; ++i) {
            int orow = r0 + lkg * 4 + i;
            if (orow < N) {
                float dv = dinv[orow];
#pragma unroll
                for (int n = 0; n < 4; ++n)
                    g[(size_t)orow * D + n * 16 + lcol] = f2bf(acc[n][i] * dv);
            }
        }
    }
}

// ---------------- aggregate v9: v7 + wave-uniform group-count branch -----
// Eighth-wave ushort8 gather (8 rows/instr). All lanes share n, so the
// branch on ng is wave-uniform: issue exactly 2, 3, or 4 flat groups
// instead of always 4 (cuts ~25-50% wasted masked gathers; mean cnt~17).
__global__ __launch_bounds__(256) void k_aggregate9(const int* __restrict__ row_ptr,
                                                    const int* __restrict__ counts,
                                                    const int* __restrict__ sorted_src,
                                                    const u16x8* __restrict__ g8,
                                                    const float* __restrict__ dinv,
                                                    const float* __restrict__ b,
                                                    float* __restrict__ out, int N) {
    int n = (blockIdx.x * 256 + threadIdx.x) >> 6;
    int lane = threadIdx.x & 63;
    if (n >= N) return;
    int q8 = lane >> 3;        // edge slot within group (0..7)
    int p8 = lane & 7;         // ushort8 slot within row
    int start = row_ptr[n];
    int cnt = counts[n];
    const int* sp = sorted_src + start;

    float a0 = 0.f, a1 = 0.f, a2 = 0.f, a3 = 0.f;
    float a4 = 0.f, a5 = 0.f, a6 = 0.f, a7 = 0.f;
    {                           // self-loop term (q8==0 lanes only)
        if (q8 == 0) {
            u16x8 v = g8[(size_t)n * 8 + p8];
            a0 = bf2f(v[0]); a1 = bf2f(v[1]); a2 = bf2f(v[2]); a3 = bf2f(v[3]);
            a4 = bf2f(v[4]); a5 = bf2f(v[5]); a6 = bf2f(v[6]); a7 = bf2f(v[7]);
        }
    }

#define LIDX8(jg, I, M)                                        \
    {                                                          \
        int e_ = (jg) * 8 + q8;                                \
        bool ok_ = (e_ < cnt);                                 \
        I = ok_ ? sp[e_] : n;                                  \
        M = ok_ ? 1.f : 0.f;                                   \
    }
#define CONS8(V, M)                                            \
    {                                                          \
        a0 = fmaf(M, bf2f(V[0]), a0);                          \
        a1 = fmaf(M, bf2f(V[1]), a1);                          \
        a2 = fmaf(M, bf2f(V[2]), a2);                          \
        a3 = fmaf(M, bf2f(V[3]), a3);                          \
        a4 = fmaf(M, bf2f(V[4]), a4);                          \
        a5 = fmaf(M, bf2f(V[5]), a5);                          \
        a6 = fmaf(M, bf2f(V[6]), a6);                          \
        a7 = fmaf(M, bf2f(V[7]), a7);                          \
    }

    int ng = (cnt + 7) >> 3;   // uniform across the wave
    if (ng <= 2) {             // cnt <= 16 (~46% of nodes)
        int i0, i1; float m0, m1;
        LIDX8(0, i0, m0); LIDX8(1, i1, m1);
        u16x8 u0 = g8[(size_t)i0 * 8 + p8];
        u16x8 u1 = g8[(size_t)i1 * 8 + p8];
        CONS8(u0, m0); CONS8(u1, m1);
    } else if (ng == 3) {      // cnt <= 24 (~51%)
        int i0, i1, i2; float m0, m1, m2;
        LIDX8(0, i0, m0); LIDX8(1, i1, m1); LIDX8(2, i2, m2);
        u16x8 u0 = g8[(size_t)i0 * 8 + p8];
        u16x8 u1 = g8[(size_t)i1 * 8 + p8];
        u16x8 u2 = g8[(size_t)i2 * 8 + p8];
        CONS8(u0, m0); CONS8(u1, m1); CONS8(u2, m2);
    } else {                   // cnt > 24 (~3%)
        int i0, i1, i2, i3; float m0, m1, m2, m3;
        LIDX8(0, i0, m0); LIDX8(1, i1, m1); LIDX8(2, i2, m2); LIDX8(3, i3, m3);
        u16x8 u0 = g8[(size_t)i0 * 8 + p8];
        u16x8 u1 = g8[(size_t)i1 * 8 + p8];
        u16x8 u2 = g8[(size_t)i2 * 8 + p8];
        u16x8 u3 = g8[(size_t)i3 * 8 + p8];
        CONS8(u0, m0); CONS8(u1, m1); CONS8(u2, m2); CONS8(u3, m3);
        for (int jg = 4; jg < ng; ++jg) {   // rare: cnt > 32
            int I; float M;
            LIDX8(jg, I, M);
            u16x8 U = g8[(size_t)I * 8 + p8];
            CONS8(U, M);
        }
    }
#undef LIDX8
#undef CONS8

    // fold the 8 edge-slots (q8) down to q8==0
#define FOLD(A) A += __shfl_xor(A, 8, 64); A += __shfl_xor(A, 16, 64); A += __shfl_xor(A, 32, 64);
    FOLD(a0) FOLD(a1) FOLD(a2) FOLD(a3) FOLD(a4) FOLD(a5) FOLD(a6) FOLD(a7)
#undef FOLD

    if (q8 == 0) {             // lanes 0..7: features 8*p8..8*p8+7
        float dv = dinv[n];
        const float4* b4 = (const float4*)b;
        float4 bl = b4[p8 * 2 + 0];
        float4 bh = b4[p8 * 2 + 1];
        float4 r0, r1;
        r0.x = fmaxf(fmaf(a0, dv, bl.x), 0.f);
        r0.y = fmaxf(fmaf(a1, dv, bl.y), 0.f);
        r0.z = fmaxf(fmaf(a2, dv, bl.z), 0.f);
        r0.w = fmaxf(fmaf(a3, dv, bl.w), 0.f);
        r1.x = fmaxf(fmaf(a4, dv, bh.x), 0.f);
        r1.y = fmaxf(fmaf(a5, dv, bh.y), 0.f);
        r1.z = fmaxf(fmaf(a6, dv, bh.z), 0.f);
        r1.w = fmaxf(fmaf(a7, dv, bh.w), 0.f);
        float4* o4 = (float4*)out;
        o4[(size_t)n * 16 + p8 * 2 + 0] = r0;
        o4[(size_t)n * 16 + p8 * 2 + 1] = r1;
    }
}

// ---------------- tier-3 (atomic fallback) ----------------

__global__ void k_deg_init(float* __restrict__ deg, int N) {
    int i = blockIdx.x * blockDim.x + threadIdx.x;
    if (i < N) deg[i] = 1.0f;
}
__global__ void k_deg_count(const int* __restrict__ dst, float* __restrict__ deg, int E) {
    int i = blockIdx.x * blockDim.x + threadIdx.x;
    if (i < E) atomicAdd(&deg[dst[i]], 1.0f);
}
__global__ void k_dinv_f(float* __restrict__ deg, int N) {
    int i = blockIdx.x * blockDim.x + threadIdx.x;
    if (i < N) deg[i] = rsqrtf(deg[i]);
}
__global__ __launch_bounds__(256) void k_gemm_fb(const float* __restrict__ x, const float* __restrict__ W,
                                                 const float* __restrict__ dinv, float* __restrict__ g,
                                                 float* __restrict__ acc, int N) {
    __shared__ float Ws[D * D];
    __shared__ float xs[4][D];
    int tid = threadIdx.x;
    for (int t = tid; t < D * D; t += 256) Ws[t] = W[t];
    int rg = tid >> 6, j = tid & 63;
    int r = blockIdx.x * 4 + rg;
    if (r < N) xs[rg][j] = x[r * D + j];
    __syncthreads();
    if (r < N) {
        float s = 0.f;
#pragma unroll
        for (int k = 0; k < D; ++k) s = fmaf(xs[rg][k], Ws[k * D + j], s);
        s *= dinv[r];
        g[r * D + j] = s;
        acc[r * D + j] = s;
    }
}
__global__ __launch_bounds__(256) void k_scatter_fb(const int* __restrict__ src, const int* __restrict__ dst,
                                                    const float* __restrict__ g, float* __restrict__ acc, int E) {
    long long idx = (long long)blockIdx.x * blockDim.x + threadIdx.x;
    int e = (int)(idx >> 6), j = (int)(idx & 63);
    if (e < E) atomicAdd(&acc[dst[e] * D + j], g[src[e] * D + j]);
}
__global__ void k_final_fb(float* __restrict__ out, const float* __restrict__ dinv,
                           const float* __restrict__ b, int N) {
    int idx = blockIdx.x * blockDim.x + threadIdx.x;
    if (idx < N * D) {
        int r = idx >> 6, j = idx & 63;
        float v = out[idx] * dinv[r] + b[j];
        out[idx] = v > 0.f ? v : 0.f;
    }
}

// ---------------- launch ----------------

extern "C" void kernel_launch(void* const* d_in, const int* in_sizes, int n_in,
                              void* d_out, int out_size, void* d_ws, size_t ws_size,
                              hipStream_t stream) {
    const float* x  = (const float*)d_in[0];
    const int*   ei = (const int*)d_in[1];
    const float* W  = (const float*)d_in[2];
    const float* b  = (const float*)d_in[3];
    float* out = (float*)d_out;

    const int N = in_sizes[0] / D;   // 80000
    const int E = in_sizes[1] / 2;   // 1280000
    const int* src = ei;
    const int* dst = ei + E;
    const int NBINS = (N + NODES_PER_BIN - 1) >> BIN_SHIFT;

    size_t off = 0;
    auto take = [&](size_t bytes) { size_t p = off; off = (off + bytes + 255) & ~(size_t)255; return p; };
    char* base = (char*)d_ws;
    size_t o_counts  = take((size_t)N * 4);
    size_t o_dinv    = take((size_t)N * 4);
    size_t o_rowptr  = take((size_t)N * 4);
    size_t o_cursor  = take(512 * 4);
    size_t o_sorted  = take((size_t)NBINS * CAP * 4);   // padded
    size_t o_binned  = take((size_t)NBINS * CAP * 4);   // padded
    size_t o_g       = take((size_t)N * D * 2);         // bf16 g
    size_t req1 = off;

    bool tier1_ok = (ws_size >= req1) && (N <= (1 << 17)) && (NBINS <= 512);

    if (tier1_ok) {
        int* counts     = (int*)(base + o_counts);
        float* dinv     = (float*)(base + o_dinv);
        int* row_ptr    = (int*)(base + o_rowptr);
        int* cursor     = (int*)(base + o_cursor);
        int* sorted_src = (int*)(base + o_sorted);
        int* binned     = (int*)(base + o_binned);
        unsigned short* g = (unsigned short*)(base + o_g);

        k_zero_i<<<1, 512, 0, stream>>>(cursor, NBINS);
        k_passA<<<(E + TILE - 1) / TILE, 256, 0, stream>>>(src, dst, cursor, binned, E, NBINS);
        k_passB<<<NBINS, 256, 0, stream>>>(binned, cursor, sorted_src, row_ptr, counts, dinv, N);
        k_gemm_v4<<<625, 256, 0, stream>>>(x, W, dinv, g, N);
        long long thr = (long long)N * 64;
        k_aggregate9<<<(int)((thr + 255) / 256), 256, 0, stream>>>(row_ptr, counts, sorted_src,
                                                                   (const u16x8*)g, dinv, b, out, N);
        return;
    }

    // tier 3: atomic fallback (fp32 end-to-end, ~21 MB ws)
    {
        float* deg = (float*)d_ws;
        float* g   = (float*)((char*)d_ws + (size_t)N * sizeof(float));
        k_deg_init<<<(N + 255) / 256, 256, 0, stream>>>(deg, N);
        k_deg_count<<<(E + 255) / 256, 256, 0, stream>>>(dst, deg, E);
        k_dinv_f<<<(N + 255) / 256, 256, 0, stream>>>(deg, N);
        k_gemm_fb<<<(N + 3) / 4, 256, 0, stream>>>(x, W, deg, g, out, N);
        long long total = (long long)E * D;
        k_scatter_fb<<<(int)((total + 255) / 256), 256, 0, stream>>>(src, dst, g, out, E);
        k_final_fb<<<(N * D + 255) / 256, 256, 0, stream>>>(out, deg, b, N);
    }
}

// Round 21
// 85.010 us; speedup vs baseline: 1.2507x; 1.0033x over previous
//
#include <hip/hip_runtime.h>
#include <hip/hip_bf16.h>

#define D 64
#define NODES_PER_BIN 256
#define BIN_SHIFT 8
#define CAP 5120          // padded per-bin capacity (mean 4096, sd ~64 -> +16 sigma)
#define TILE 2048
#define EPT 8             // TILE / 256
#define WSTR 72           // padded LDS stride for transposed W (bank-spread)

typedef short bf16x8 __attribute__((ext_vector_type(8)));
typedef float f32x4 __attribute__((ext_vector_type(4)));
typedef unsigned short u16x8 __attribute__((ext_vector_type(8)));

// bf16 helpers (finite data only)
__device__ __forceinline__ float bf2f(unsigned short u) {
    union { unsigned int i; float f; } c; c.i = (unsigned int)u << 16; return c.f;
}
__device__ __forceinline__ unsigned short f2bf(float f) {
    union { float f; unsigned int i; } c; c.f = f;
    unsigned int x = c.i;
    return (unsigned short)((x + 0x7fffu + ((x >> 16) & 1u)) >> 16);  // RNE
}

// tiny zero kernel (1 block, ~2 us)
__global__ void k_zero_i(int* __restrict__ p, int n) {
    int i = threadIdx.x;
    if (i < n) p[i] = 0;
}

// ---- passA v3: direct-write multisplit, dual lane-half sub-histograms ---
// (halves intra-instruction LDS-atomic collision depth vs one histogram)
// packed word: src | dstLocal<<17   (requires N <= 2^17)
__global__ __launch_bounds__(256) void k_passA(const int* __restrict__ src,
                                               const int* __restrict__ dst,
                                               int* __restrict__ cursor,      // [NBINS], zeroed
                                               int* __restrict__ binned,      // [NBINS*CAP]
                                               int E, int NBINS) {
    __shared__ int hist0[512];
    __shared__ int hist1[512];
    __shared__ int reservedBase[512];
    int tid = threadIdx.x;
    int h = (tid >> 5) & 1;            // lane-half (lanes 0-31 vs 32-63)
    long long t0 = (long long)blockIdx.x * TILE;
    int cnt_tile = (int)((E - t0 < TILE) ? (E - t0) : TILE);

    for (int i = tid; i < 512; i += 256) { hist0[i] = 0; hist1[i] = 0; }
    __syncthreads();

    int* myh = h ? hist1 : hist0;
    int val[EPT]; int bn[EPT]; int rk[EPT];
#pragma unroll
    for (int k = 0; k < EPT; ++k) {
        int i = k * 256 + tid;
        if (i < cnt_tile) {
            int e = (int)t0 + i;
            int s = src[e], d = dst[e];
            bn[k] = d >> BIN_SHIFT;
            val[k] = s | ((d & (NODES_PER_BIN - 1)) << 17);
            rk[k] = atomicAdd(&myh[bn[k]], 1);   // rank within sub-hist
        } else { bn[k] = -1; val[k] = 0; rk[k] = 0; }
    }
    __syncthreads();
    for (int i = tid; i < NBINS; i += 256) {
        int tot = hist0[i] + hist1[i];
        reservedBase[i] = (tot > 0) ? atomicAdd(&cursor[i], tot) : 0;
    }
    __syncthreads();
#pragma unroll
    for (int k = 0; k < EPT; ++k)
        if (bn[k] >= 0) {
            int off = reservedBase[bn[k]] + (h ? hist0[bn[k]] : 0) + rk[k];
            binned[bn[k] * CAP + off] = val[k];
        }
}

// ---- passB: per-bin LDS counting sort -> sorted_src (padded), rc=(start,
//      count) packed int2, dinv. start = b*CAP + local offset. ----
__global__ __launch_bounds__(256) void k_passB(const int* __restrict__ binned,
                                               const int* __restrict__ binCount,  // = cursor after passA
                                               int* __restrict__ sorted_src,      // [NBINS*CAP]
                                               int2* __restrict__ rc,             // [N] (start,count)
                                               float* __restrict__ dinv, int N) {
    __shared__ int eLDS[CAP];
    __shared__ int srt[CAP];
    __shared__ int cnt[NODES_PER_BIN];
    __shared__ int nodeOff[NODES_PER_BIN];
    __shared__ int sA[NODES_PER_BIN], sB[NODES_PER_BIN];
    int tid = threadIdx.x;
    int b = blockIdx.x;
    int lo = b << BIN_SHIFT;
    int nNodes = N - lo; if (nNodes > NODES_PER_BIN) nNodes = NODES_PER_BIN;
    int base = b * CAP;
    int size = binCount[b]; if (size > CAP) size = CAP;

    for (int i = tid; i < size; i += 256) eLDS[i] = binned[base + i];
    cnt[tid] = 0;
    __syncthreads();
    for (int i = tid; i < size; i += 256) atomicAdd(&cnt[eLDS[i] >> 17], 1);
    __syncthreads();
    sA[tid] = cnt[tid];
    __syncthreads();
    int *a = sA, *bb = sB;
    for (int dd = 1; dd < 256; dd <<= 1) {
        bb[tid] = a[tid] + (tid >= dd ? a[tid - dd] : 0);
        __syncthreads();
        int* t = a; a = bb; bb = t;
    }
    nodeOff[tid] = (tid > 0) ? a[tid - 1] : 0;
    __syncthreads();
    if (tid < nNodes) {
        int c = cnt[tid];
        rc[lo + tid] = make_int2(base + nodeOff[tid], c);
        dinv[lo + tid] = rsqrtf(1.0f + (float)c);
    }
    __syncthreads();
    cnt[tid] = 0;
    __syncthreads();
    for (int i = tid; i < size; i += 256) {
        int v = eLDS[i];
        int dl = v >> 17;
        int r = atomicAdd(&cnt[dl], 1);
        srt[nodeOff[dl] + r] = v & 0x1FFFF;
    }
    __syncthreads();
    for (int i = tid; i < size; i += 256) sorted_src[base + i] = srt[i];
}

// ---------------- g = bf16((x @ W) * dinv[row]) via MFMA, persistent ----
__global__ __launch_bounds__(256) void k_gemm_v4(const float* __restrict__ x,
                                                 const float* __restrict__ W,
                                                 const float* __restrict__ dinv,
                                                 unsigned short* __restrict__ g, int N) {
    __shared__ unsigned short WtHi[D * WSTR];  // 9 KB
    __shared__ unsigned short WtLo[D * WSTR];  // 9 KB
    int tid = threadIdx.x;
    for (int idx = tid; idx < D * D; idx += 256) {
        int k = idx >> 6, j = idx & 63;
        float w = W[idx];                    // W[k][j]
        unsigned short hi = f2bf(w);
        WtHi[j * WSTR + k] = hi;
        WtLo[j * WSTR + k] = f2bf(w - bf2f(hi));
    }
    __syncthreads();

    int lane = tid & 63;
    int wid  = tid >> 6;
    int lcol = lane & 15;
    int lkg  = lane >> 4;

    bf16x8 Bhi[2][4], Blo[2][4];
#pragma unroll
    for (int s = 0; s < 2; ++s)
#pragma unroll
        for (int n = 0; n < 4; ++n) {
            int j = n * 16 + lcol;
            int k = s * 32 + lkg * 8;
            Bhi[s][n] = *(const bf16x8*)&WtHi[j * WSTR + k];
            Blo[s][n] = *(const bf16x8*)&WtLo[j * WSTR + k];
        }

    const int nTiles = (N + 15) >> 4;
    const int stride = gridDim.x * 4;
    for (int t = blockIdx.x * 4 + wid; t < nTiles; t += stride) {
        int r0 = t * 16;
        int arow = r0 + lcol;
        bool rok = (arow < N);
        bf16x8 Ahi[2], Alo[2];
#pragma unroll
        for (int s = 0; s < 2; ++s) {
            float4 v0{0.f,0.f,0.f,0.f}, v1{0.f,0.f,0.f,0.f};
            if (rok) {
                const float4* p = (const float4*)&x[(size_t)arow * D + s * 32 + lkg * 8];
                v0 = p[0]; v1 = p[1];
            }
            float xv[8] = {v0.x, v0.y, v0.z, v0.w, v1.x, v1.y, v1.z, v1.w};
#pragma unroll
            for (int e = 0; e < 8; ++e) {
                unsigned short hi = f2bf(xv[e]);
                Ahi[s][e] = (short)hi;
                Alo[s][e] = (short)f2bf(xv[e] - bf2f(hi));
            }
        }

        f32x4 acc[4];
#pragma unroll
        for (int n = 0; n < 4; ++n) {
            f32x4 c = {0.f, 0.f, 0.f, 0.f};
            c = __builtin_amdgcn_mfma_f32_16x16x32_bf16(Ahi[0], Bhi[0][n], c, 0, 0, 0);
            c = __builtin_amdgcn_mfma_f32_16x16x32_bf16(Ahi[1], Bhi[1][n], c, 0, 0, 0);
            c = __builtin_amdgcn_mfma_f32_16x16x32_bf16(Alo[0], Bhi[0][n], c, 0, 0, 0);
            c = __builtin_amdgcn_mfma_f32_16x16x32_bf16(Alo[1], Bhi[1][n], c, 0, 0, 0);
            c = __builtin_amdgcn_mfma_f32_16x16x32_bf16(Ahi[0], Blo[0][n], c, 0, 0, 0);
            c = __builtin_amdgcn_mfma_f32_16x16x32_bf16(Ahi[1], Blo[1][n], c, 0, 0, 0);
            acc[n] = c;
        }

#pragma unroll
        for (int i = 0; i < 4; ++i) {
            int orow = r0 + lkg * 4 + i;
            if (orow < N) {
                float dv = dinv[orow];
#pragma unroll
                for (int n = 0; n < 4; ++n)
                    g[(size_t)orow * D + n * 16 + lcol] = f2bf(acc[n][i] * dv);
            }
        }
    }
}

// ---------------- aggregate v10: v9 + packed (start,count) int2 ----------
__global__ __launch_bounds__(256) void k_aggregate10(const int2* __restrict__ rc,
                                                     const int* __restrict__ sorted_src,
                                                     const u16x8* __restrict__ g8,
                                                     const float* __restrict__ dinv,
                                                     const float* __restrict__ b,
                                                     float* __restrict__ out, int N) {
    int n = (blockIdx.x * 256 + threadIdx.x) >> 6;
    int lane = threadIdx.x & 63;
    if (n >= N) return;
    int q8 = lane >> 3;        // edge slot within group (0..7)
    int p8 = lane & 7;         // ushort8 slot within row
    int2 se = rc[n];
    int start = se.x, cnt = se.y;
    const int* sp = sorted_src + start;

    float a0 = 0.f, a1 = 0.f, a2 = 0.f, a3 = 0.f;
    float a4 = 0.f, a5 = 0.f, a6 = 0.f, a7 = 0.f;
    if (q8 == 0) {             // self-loop term
        u16x8 v = g8[(size_t)n * 8 + p8];
        a0 = bf2f(v[0]); a1 = bf2f(v[1]); a2 = bf2f(v[2]); a3 = bf2f(v[3]);
        a4 = bf2f(v[4]); a5 = bf2f(v[5]); a6 = bf2f(v[6]); a7 = bf2f(v[7]);
    }

#define LIDX8(jg, I, M)                                        \
    {                                                          \
        int e_ = (jg) * 8 + q8;                                \
        bool ok_ = (e_ < cnt);                                 \
        I = ok_ ? sp[e_] : n;                                  \
        M = ok_ ? 1.f : 0.f;                                   \
    }
#define CONS8(V, M)                                            \
    {                                                          \
        a0 = fmaf(M, bf2f(V[0]), a0);                          \
        a1 = fmaf(M, bf2f(V[1]), a1);                          \
        a2 = fmaf(M, bf2f(V[2]), a2);                          \
        a3 = fmaf(M, bf2f(V[3]), a3);                          \
        a4 = fmaf(M, bf2f(V[4]), a4);                          \
        a5 = fmaf(M, bf2f(V[5]), a5);                          \
        a6 = fmaf(M, bf2f(V[6]), a6);                          \
        a7 = fmaf(M, bf2f(V[7]), a7);                          \
    }

    int ng = (cnt + 7) >> 3;   // uniform across the wave
    if (ng <= 2) {             // cnt <= 16 (~46% of nodes)
        int i0, i1; float m0, m1;
        LIDX8(0, i0, m0); LIDX8(1, i1, m1);
        u16x8 u0 = g8[(size_t)i0 * 8 + p8];
        u16x8 u1 = g8[(size_t)i1 * 8 + p8];
        CONS8(u0, m0); CONS8(u1, m1);
    } else if (ng == 3) {      // cnt <= 24 (~51%)
        int i0, i1, i2; float m0, m1, m2;
        LIDX8(0, i0, m0); LIDX8(1, i1, m1); LIDX8(2, i2, m2);
        u16x8 u0 = g8[(size_t)i0 * 8 + p8];
        u16x8 u1 = g8[(size_t)i1 * 8 + p8];
        u16x8 u2 = g8[(size_t)i2 * 8 + p8];
        CONS8(u0, m0); CONS8(u1, m1); CONS8(u2, m2);
    } else {                   // cnt > 24 (~3%)
        int i0, i1, i2, i3; float m0, m1, m2, m3;
        LIDX8(0, i0, m0); LIDX8(1, i1, m1); LIDX8(2, i2, m2); LIDX8(3, i3, m3);
        u16x8 u0 = g8[(size_t)i0 * 8 + p8];
        u16x8 u1 = g8[(size_t)i1 * 8 + p8];
        u16x8 u2 = g8[(size_t)i2 * 8 + p8];
        u16x8 u3 = g8[(size_t)i3 * 8 + p8];
        CONS8(u0, m0); CONS8(u1, m1); CONS8(u2, m2); CONS8(u3, m3);
        for (int jg = 4; jg < ng; ++jg) {   // rare: cnt > 32
            int I; float M;
            LIDX8(jg, I, M);
            u16x8 U = g8[(size_t)I * 8 + p8];
            CONS8(U, M);
        }
    }
#undef LIDX8
#undef CONS8

    // fold the 8 edge-slots (q8) down to q8==0
#define FOLD(A) A += __shfl_xor(A, 8, 64); A += __shfl_xor(A, 16, 64); A += __shfl_xor(A, 32, 64);
    FOLD(a0) FOLD(a1) FOLD(a2) FOLD(a3) FOLD(a4) FOLD(a5) FOLD(a6) FOLD(a7)
#undef FOLD

    if (q8 == 0) {             // lanes 0..7: features 8*p8..8*p8+7
        float dv = dinv[n];
        const float4* b4 = (const float4*)b;
        float4 bl = b4[p8 * 2 + 0];
        float4 bh = b4[p8 * 2 + 1];
        float4 r0, r1;
        r0.x = fmaxf(fmaf(a0, dv, bl.x), 0.f);
        r0.y = fmaxf(fmaf(a1, dv, bl.y), 0.f);
        r0.z = fmaxf(fmaf(a2, dv, bl.z), 0.f);
        r0.w = fmaxf(fmaf(a3, dv, bl.w), 0.f);
        r1.x = fmaxf(fmaf(a4, dv, bh.x), 0.f);
        r1.y = fmaxf(fmaf(a5, dv, bh.y), 0.f);
        r1.z = fmaxf(fmaf(a6, dv, bh.z), 0.f);
        r1.w = fmaxf(fmaf(a7, dv, bh.w), 0.f);
        float4* o4 = (float4*)out;
        o4[(size_t)n * 16 + p8 * 2 + 0] = r0;
        o4[(size_t)n * 16 + p8 * 2 + 1] = r1;
    }
}

// ---------------- tier-3 (atomic fallback) ----------------

__global__ void k_deg_init(float* __restrict__ deg, int N) {
    int i = blockIdx.x * blockDim.x + threadIdx.x;
    if (i < N) deg[i] = 1.0f;
}
__global__ void k_deg_count(const int* __restrict__ dst, float* __restrict__ deg, int E) {
    int i = blockIdx.x * blockDim.x + threadIdx.x;
    if (i < E) atomicAdd(&deg[dst[i]], 1.0f);
}
__global__ void k_dinv_f(float* __restrict__ deg, int N) {
    int i = blockIdx.x * blockDim.x + threadIdx.x;
    if (i < N) deg[i] = rsqrtf(deg[i]);
}
__global__ __launch_bounds__(256) void k_gemm_fb(const float* __restrict__ x, const float* __restrict__ W,
                                                 const float* __restrict__ dinv, float* __restrict__ g,
                                                 float* __restrict__ acc, int N) {
    __shared__ float Ws[D * D];
    __shared__ float xs[4][D];
    int tid = threadIdx.x;
    for (int t = tid; t < D * D; t += 256) Ws[t] = W[t];
    int rg = tid >> 6, j = tid & 63;
    int r = blockIdx.x * 4 + rg;
    if (r < N) xs[rg][j] = x[r * D + j];
    __syncthreads();
    if (r < N) {
        float s = 0.f;
#pragma unroll
        for (int k = 0; k < D; ++k) s = fmaf(xs[rg][k], Ws[k * D + j], s);
        s *= dinv[r];
        g[r * D + j] = s;
        acc[r * D + j] = s;
    }
}
__global__ __launch_bounds__(256) void k_scatter_fb(const int* __restrict__ src, const int* __restrict__ dst,
                                                    const float* __restrict__ g, float* __restrict__ acc, int E) {
    long long idx = (long long)blockIdx.x * blockDim.x + threadIdx.x;
    int e = (int)(idx >> 6), j = (int)(idx & 63);
    if (e < E) atomicAdd(&acc[dst[e] * D + j], g[src[e] * D + j]);
}
__global__ void k_final_fb(float* __restrict__ out, const float* __restrict__ dinv,
                           const float* __restrict__ b, int N) {
    int idx = blockIdx.x * blockDim.x + threadIdx.x;
    if (idx < N * D) {
        int r = idx >> 6, j = idx & 63;
        float v = out[idx] * dinv[r] + b[j];
        out[idx] = v > 0.f ? v : 0.f;
    }
}

// ---------------- launch ----------------

extern "C" void kernel_launch(void* const* d_in, const int* in_sizes, int n_in,
                              void* d_out, int out_size, void* d_ws, size_t ws_size,
                              hipStream_t stream) {
    const float* x  = (const float*)d_in[0];
    const int*   ei = (const int*)d_in[1];
    const float* W  = (const float*)d_in[2];
    const float* b  = (const float*)d_in[3];
    float* out = (float*)d_out;

    const int N = in_sizes[0] / D;   // 80000
    const int E = in_sizes[1] / 2;   // 1280000
    const int* src = ei;
    const int* dst = ei + E;
    const int NBINS = (N + NODES_PER_BIN - 1) >> BIN_SHIFT;

    size_t off = 0;
    auto take = [&](size_t bytes) { size_t p = off; off = (off + bytes + 255) & ~(size_t)255; return p; };
    char* base = (char*)d_ws;
    size_t o_rc      = take((size_t)N * 8);             // int2 (start,count)
    size_t o_dinv    = take((size_t)N * 4);
    size_t o_cursor  = take(512 * 4);
    size_t o_sorted  = take((size_t)NBINS * CAP * 4);   // padded
    size_t o_binned  = take((size_t)NBINS * CAP * 4);   // padded
    size_t o_g       = take((size_t)N * D * 2);         // bf16 g
    size_t req1 = off;

    bool tier1_ok = (ws_size >= req1) && (N <= (1 << 17)) && (NBINS <= 512);

    if (tier1_ok) {
        int2* rc        = (int2*)(base + o_rc);
        float* dinv     = (float*)(base + o_dinv);
        int* cursor     = (int*)(base + o_cursor);
        int* sorted_src = (int*)(base + o_sorted);
        int* binned     = (int*)(base + o_binned);
        unsigned short* g = (unsigned short*)(base + o_g);

        k_zero_i<<<1, 512, 0, stream>>>(cursor, NBINS);
        k_passA<<<(E + TILE - 1) / TILE, 256, 0, stream>>>(src, dst, cursor, binned, E, NBINS);
        k_passB<<<NBINS, 256, 0, stream>>>(binned, cursor, sorted_src, rc, dinv, N);
        k_gemm_v4<<<625, 256, 0, stream>>>(x, W, dinv, g, N);
        long long thr = (long long)N * 64;
        k_aggregate10<<<(int)((thr + 255) / 256), 256, 0, stream>>>(rc, sorted_src,
                                                                    (const u16x8*)g, dinv, b, out, N);
        return;
    }

    // tier 3: atomic fallback (fp32 end-to-end, ~21 MB ws)
    {
        float* deg = (float*)d_ws;
        float* g   = (float*)((char*)d_ws + (size_t)N * sizeof(float));
        k_deg_init<<<(N + 255) / 256, 256, 0, stream>>>(deg, N);
        k_deg_count<<<(E + 255) / 256, 256, 0, stream>>>(dst, deg, E);
        k_dinv_f<<<(N + 255) / 256, 256, 0, stream>>>(deg, N);
        k_gemm_fb<<<(N + 3) / 4, 256, 0, stream>>>(x, W, deg, g, out, N);
        long long total = (long long)E * D;
        k_scatter_fb<<<(int)((total + 255) / 256), 256, 0, stream>>>(src, dst, g, out, E);
        k_final_fb<<<(N * D + 255) / 256, 256, 0, stream>>>(out, deg, b, N);
    }
}